// Round 6
// baseline (318.570 us; speedup 1.0000x reference)
//
#include <hip/hip_runtime.h>
#include <hip/hip_bf16.h>

typedef __attribute__((ext_vector_type(8))) short s16x8;
typedef __attribute__((ext_vector_type(4))) float f32x4;

#define D_IN 227989
#define KSPLIT 128
#define KC 1792        // 28*64; KSPLIT*KC = 229376 >= D_IN
#define NSTEPS 28      // K-step 64
#define APITCH 68      // dwords per LDS row: 64 shifted data + up-to-3 shift + tail chunk
#define BUFSZ (128 * APITCH)   // per buffer: A rows 0..63, B rows 64..127

__device__ __forceinline__ unsigned short f2bf(float f) {
    unsigned int u = __float_as_uint(f);
    u = (u + 0x7FFFu + ((u >> 16) & 1u)) >> 16;
    return (unsigned short)u;
}

// 8 consecutive f32 (only 4B-aligned) in LDS -> bf16 fragment
__device__ __forceinline__ s16x8 cvt8u(const float* p) {
    s16x8 r;
    #pragma unroll
    for (int e = 0; e < 8; ++e) r[e] = (short)f2bf(p[e]);
    return r;
}

// register-staged tile: 4 A-chunks + 4 B-chunks (f32x4/lane) + tail chunk
struct Stg {
    f32x4 a0, a1, a2, a3, b0, b1, b2, b3, tl;
};

__device__ __forceinline__ void load_set(Stg& S, const float* pxa, const float* pwa,
                                         const float* ptl, int lane, int s) {
    const long o = (long)s * 64;
    S.a0 = *(const f32x4*)(pxa + o);
    S.a1 = *(const f32x4*)(pxa + o + 4l * D_IN);
    S.a2 = *(const f32x4*)(pxa + o + 8l * D_IN);
    S.a3 = *(const f32x4*)(pxa + o + 12l * D_IN);
    S.b0 = *(const f32x4*)(pwa + o);
    S.b1 = *(const f32x4*)(pwa + o + 4l * D_IN);
    S.b2 = *(const f32x4*)(pwa + o + 8l * D_IN);
    S.b3 = *(const f32x4*)(pwa + o + 12l * D_IN);
    if (lane < 32) S.tl = *(const f32x4*)(ptl + o);
}

__device__ __forceinline__ void write_set(const Stg& S, float* buf,
                                          int wid, int rr, int ll, int lane) {
    float* pa = buf + (wid * 16 + rr) * APITCH + ll * 4;
    *(f32x4*)(pa) = S.a0;
    *(f32x4*)(pa + 4 * APITCH) = S.a1;
    *(f32x4*)(pa + 8 * APITCH) = S.a2;
    *(f32x4*)(pa + 12 * APITCH) = S.a3;
    float* pb = buf + (64 + wid * 16 + rr) * APITCH + ll * 4;
    *(f32x4*)(pb) = S.b0;
    *(f32x4*)(pb + 4 * APITCH) = S.b1;
    *(f32x4*)(pb + 8 * APITCH) = S.b2;
    *(f32x4*)(pb + 12 * APITCH) = S.b3;
    if (lane < 32) {
        const int lr = (lane < 16) ? (wid * 16 + lane) : (64 + wid * 16 + lane - 16);
        *(f32x4*)(buf + lr * APITCH + 64) = S.tl;
    }
}

// one K-step-64 of MFMAs; row r's data sits shifted by (r&3)==(frow&3) dwords
__device__ __forceinline__ void compute_tile(const float* buf, int wid,
                                             int frow, int koct, f32x4* acc) {
    const int off = (frow & 3) + koct * 8;
    const float* B = buf + (64 + wid * 16 + frow) * APITCH + off;
    const s16x8 b0 = cvt8u(B);
    const s16x8 b1 = cvt8u(B + 32);
    #pragma unroll
    for (int m = 0; m < 4; ++m) {
        const float* A = buf + (m * 16 + frow) * APITCH + off;
        acc[m] = __builtin_amdgcn_mfma_f32_16x16x32_bf16(cvt8u(A), b0, acc[m], 0, 0, 0);
        acc[m] = __builtin_amdgcn_mfma_f32_16x16x32_bf16(cvt8u(A + 32), b1, acc[m], 0, 0, 0);
    }
}

__device__ __forceinline__ void bar() {
    asm volatile("s_waitcnt lgkmcnt(0)\n\ts_barrier" ::: "memory");
}

// ---------------------------------------------------------------- K1: FC GEMM
// C[64,512] = x[64,K] @ fc_w[512,K]^T, bf16 MFMA, K-split partials.
// Block tile M=64 x N=64 x K=64, 4 waves. Staging: float4 register loads from
// the per-row ALIGNED-DOWN window (row misalignment == r&3), ds_write_b128
// into pitch-68 LDS rows (+16B tail chunk), double-buffered; raw
// lgkmcnt+s_barrier only -- global loads stay in flight across barriers
// (compiler emits exact counted vmcnt before the LDS writes).
__global__ __launch_bounds__(256) void k_fc_gemm(const float* __restrict__ x,
                                                 const float* __restrict__ w,
                                                 float* __restrict__ part) {
    __shared__ __align__(16) float lds[2 * BUFSZ];   // 68 KiB -> 2 blocks/CU
    const int t = threadIdx.x;
    const int wid = t >> 6, lane = t & 63;
    const int frow = lane & 15, koct = lane >> 4;
    const int rr = lane >> 4, ll = lane & 15;        // staging decomposition
    const int bx = blockIdx.x;
    const int nt = bx & 7, ks = bx >> 3;
    const long k0 = (long)ks * KC;

    float* L0 = lds;
    float* L1 = lds + BUFSZ;

    f32x4 acc[4] = {};

    if (k0 + KC <= D_IN) {
        // -------- fast path (ks 0..126)
        const float* pxa = x + (long)(wid * 16 + rr) * D_IN + k0 - rr + ll * 4;
        const float* pwa = w + (long)(nt * 64 + wid * 16 + rr) * D_IN + k0 - rr + ll * 4;
        const int Lr = lane & 15;
        const float* ptl = ((lane < 16) ? (x + (long)(wid * 16 + Lr) * D_IN)
                                        : (w + (long)(nt * 64 + wid * 16 + Lr) * D_IN))
                           + k0 + 64 - (Lr & 3);

        Stg SA, SB;
        load_set(SA, pxa, pwa, ptl, lane, 0);
        load_set(SB, pxa, pwa, ptl, lane, 1);
        write_set(SA, L0, wid, rr, ll, lane);
        bar();
        #pragma unroll 1
        for (int s = 0; s < NSTEPS; s += 2) {
            if (s + 2 < NSTEPS) load_set(SA, pxa, pwa, ptl, lane, s + 2);
            write_set(SB, L1, wid, rr, ll, lane);   // tile s+1
            bar();
            compute_tile(L0, wid, frow, koct, acc); // tile s
            bar();
            if (s + 3 < NSTEPS) load_set(SB, pxa, pwa, ptl, lane, s + 3);
            if (s + 2 < NSTEPS) write_set(SA, L0, wid, rr, ll, lane);  // tile s+2
            bar();
            compute_tile(L1, wid, frow, koct, acc); // tile s+1
            bar();
        }
    } else {
        // -------- tail block (ks == 127, rem = 405): predicated, shifted writes
        const int rem = (int)(D_IN - k0);
        const int nst = (rem + 63) >> 6;
        const float* ga = x + (long)(wid * 16) * D_IN + k0 + lane;
        const float* gb = w + (long)(nt * 64 + wid * 16) * D_IN + k0 + lane;
        for (int s = 0; s < nst; ++s) {
            const int kk = s * 64 + lane;
            const bool ok = kk < rem;
            float va[16], vb[16];
            #pragma unroll
            for (int i = 0; i < 16; ++i) {
                va[i] = ok ? ga[(long)i * D_IN + s * 64] : 0.0f;
                vb[i] = ok ? gb[(long)i * D_IN + s * 64] : 0.0f;
            }
            __syncthreads();
            #pragma unroll
            for (int i = 0; i < 16; ++i) {
                lds[(wid * 16 + i) * APITCH + lane + (i & 3)] = va[i];
                lds[(64 + wid * 16 + i) * APITCH + lane + (i & 3)] = vb[i];
            }
            __syncthreads();
            compute_tile(lds, wid, frow, koct, acc);
        }
    }

    // partials: chunk (g16, ks) holds [64 m][16 n]; g16 = global 16-col group
    const int g16 = nt * 4 + wid;
    float* __restrict__ po = part + ((long)(g16 * KSPLIT + ks) << 10);
    #pragma unroll
    for (int m = 0; m < 4; ++m)
        #pragma unroll
        for (int r = 0; r < 4; ++r)
            po[(m * 16 + koct * 4 + r) * 16 + frow] = acc[m][r];
}

// ------------------------------------------------- K2: reduce + bias + ReLU
__global__ __launch_bounds__(256) void k_fc_reduce(const float* __restrict__ part,
                                                   const float* __restrict__ bias,
                                                   float* __restrict__ sdae) {
    const int i = blockIdx.x * 256 + threadIdx.x;  // 32768
    const int m = i >> 9, n = i & 511;
    const int nt = n >> 4, nl = n & 15;
    const float* p = part + ((long)nt * KSPLIT << 10) + m * 16 + nl;
    float s = 0.f;
    #pragma unroll 4
    for (int ks = 0; ks < KSPLIT; ++ks) s += p[(long)ks << 10];
    s += bias[n];
    sdae[i] = fmaxf(s, 0.0f);
}

// ------------------------------------------------- K3: conv + squash -> xt
// xt[b][c][i] with c = co*253+l, i = nu.  grid 64 (b), block 256.
__global__ __launch_bounds__(256) void k_conv_squash(const float* __restrict__ sdae,
                                                     const float* __restrict__ cw,
                                                     const float* __restrict__ cb,
                                                     float* __restrict__ xt) {
    __shared__ float row_s[512];
    __shared__ float us[64 * 253];
    __shared__ float part[256];
    __shared__ float scale_s[8];
    const int b = blockIdx.x, t = threadIdx.x;
    row_s[t] = sdae[b * 512 + t];
    row_s[t + 256] = sdae[b * 512 + t + 256];
    __syncthreads();
    const int ch = t >> 2, lq = t & 3;
    float wreg[8];
    #pragma unroll
    for (int k = 0; k < 8; ++k) wreg[k] = cw[ch * 8 + k];
    const float bias = cb[ch];
    const int l0 = lq * 64;
    const int l1 = (lq == 3) ? 253 : (l0 + 64);
    float ssq = 0.f;
    for (int l = l0; l < l1; ++l) {
        float v = bias;
        #pragma unroll
        for (int k = 0; k < 8; ++k) v += row_s[2 * l + k] * wreg[k];
        us[ch * 253 + l] = v;
        ssq += v * v;
    }
    part[t] = ssq;
    __syncthreads();
    if (t < 8) {
        float s = 0.f;
        for (int i = 0; i < 32; ++i) s += part[t * 32 + i];
        scale_s[t] = sqrtf(s) / (1.0f + s);  // mag_sq/(1+mag_sq)/mag == mag/(1+mag_sq)
    }
    __syncthreads();
    const int nu = ch >> 3, co = ch & 7;
    const float sc = scale_s[nu];
    for (int l = l0; l < l1; ++l)
        xt[(long)b * 16192 + (long)(co * 253 + l) * 8 + nu] = us[ch * 253 + l] * sc;
}

// ------------------------------------------------- K4: s_j partials
// s[b,j,d] = sum_{c,i} (cij[j,c]*W[c,j,d,i]) * xt[b,c,i]
// grid = 4j * 64 csplit = 256; block 256; each WG all b,d over 32 c's.
// UNIFORM=1: first routing iteration, c_ij == 1/2024 (no cij read).
template <int UNIFORM>
__global__ __launch_bounds__(256) void k_route_s(const float* __restrict__ W,
                                                 const float* __restrict__ xt,
                                                 const float* __restrict__ cij,
                                                 float* __restrict__ spart) {
    __shared__ __align__(16) float xs[64 * 132];   // [b][128+pad]
    __shared__ __align__(16) float wsh[16 * 768];  // [cc][d*12]
    const int bx = blockIdx.x;
    const int j = bx >> 6, cs = bx & 63;
    const int c0 = cs * 32;
    const int t = threadIdx.x;
    const int bg = t >> 4, dg = t & 15;
    float acc[4][4] = {};
    #pragma unroll 1
    for (int cc0 = 0; cc0 < 32; cc0 += 16) {
        {
            const int bb = t >> 2, p = t & 3;
            const float* src = xt + (long)bb * 16192 + (long)(c0 + cc0) * 8 + p * 32;
            float* dst = &xs[bb * 132 + p * 32];
            if (c0 + cc0 + 16 <= 2024) {
                #pragma unroll
                for (int e = 0; e < 32; e += 4) *(f32x4*)(dst + e) = *(const f32x4*)(src + e);
            } else {
                for (int e = 0; e < 32; ++e) {
                    int cidx = c0 + cc0 + ((p * 32 + e) >> 3);
                    dst[e] = (cidx < 2024) ? src[e] : 0.0f;
                }
            }
        }
        {
            const int ccs = t >> 4, dp = t & 15;
            const int c = c0 + cc0 + ccs;
            float* o = &wsh[ccs * 768 + dp * 48];
            if (c < 2024) {
                const float sc = UNIFORM ? (1.0f / 2024.0f) : cij[j * 2024 + c];
                const float* wsrc = W + (long)c * 2048 + j * 512 + dp * 32;
                #pragma unroll
                for (int dd = 0; dd < 4; ++dd) {
                    f32x4 w0 = *(const f32x4*)(wsrc + dd * 8);
                    f32x4 w1 = *(const f32x4*)(wsrc + dd * 8 + 4);
                    float* od = o + dd * 12;
                    od[0] = w0[0] * sc; od[1] = w0[1] * sc; od[2] = w0[2] * sc; od[3] = w0[3] * sc;
                    od[4] = w1[0] * sc; od[5] = w1[1] * sc; od[6] = w1[2] * sc; od[7] = w1[3] * sc;
                }
            } else {
                #pragma unroll
                for (int dd = 0; dd < 4; ++dd) {
                    float* od = o + dd * 12;
                    #pragma unroll
                    for (int e = 0; e < 8; ++e) od[e] = 0.0f;
                }
            }
        }
        __syncthreads();
        int ccN = 2024 - c0 - cc0;
        if (ccN > 16) ccN = 16;
        for (int cc = 0; cc < ccN; ++cc) {
            float xv[4][8], wv[4][8];
            #pragma unroll
            for (int bb = 0; bb < 4; ++bb) {
                *(f32x4*)&xv[bb][0] = *(const f32x4*)&xs[(bg * 4 + bb) * 132 + cc * 8];
                *(f32x4*)&xv[bb][4] = *(const f32x4*)&xs[(bg * 4 + bb) * 132 + cc * 8 + 4];
            }
            #pragma unroll
            for (int dd = 0; dd < 4; ++dd) {
                const int d = dg + dd * 16;
                *(f32x4*)&wv[dd][0] = *(const f32x4*)&wsh[cc * 768 + d * 12];
                *(f32x4*)&wv[dd][4] = *(const f32x4*)&wsh[cc * 768 + d * 12 + 4];
            }
            #pragma unroll
            for (int bb = 0; bb < 4; ++bb)
                #pragma unroll
                for (int dd = 0; dd < 4; ++dd)
                    #pragma unroll
                    for (int i = 0; i < 8; ++i)
                        acc[bb][dd] += xv[bb][i] * wv[dd][i];
        }
        __syncthreads();
    }
    float* sp = spart + ((long)bx << 12);
    #pragma unroll
    for (int bb = 0; bb < 4; ++bb)
        #pragma unroll
        for (int dd = 0; dd < 4; ++dd)
            sp[(bg * 4 + bb) * 64 + dg + dd * 16] = acc[bb][dd];
}

// ------------------------------------------------- K5: reduce s + squash(j) -> v
__global__ __launch_bounds__(256) void k_route_v(const float* __restrict__ spart,
                                                 float* __restrict__ v) {
    __shared__ float sj[256];
    const int b = blockIdx.x, t = threadIdx.x;
    const int d = t & 63;
    const int j = t >> 6;
    float s = 0.f;
    #pragma unroll 4
    for (int cs = 0; cs < 64; ++cs)
        s += spart[((long)(j * 64 + cs) << 12) + (b << 6) + d];
    sj[t] = s;
    __syncthreads();
    float msq = 0.f;
    #pragma unroll
    for (int q = 0; q < 4; ++q) { float z = sj[q * 64 + d]; msq += z * z; }
    v[(b << 8) + t] = s * (sqrtf(msq) / (1.0f + msq));
}

// ------------------------------------------------- K6: agreement -> b_ij
// grid 253 (8 c's each), block 256 = (cc8, j4, p8).
template <int ADD>
__global__ __launch_bounds__(256) void k_route_a(const float* __restrict__ W,
                                                 const float* __restrict__ xt,
                                                 const float* __restrict__ v,
                                                 float* __restrict__ bij) {
    __shared__ __align__(16) float xts[64 * 68];   // [cc*8+i][b]
    __shared__ __align__(16) float vts[4 * 4360];  // j*4360 + d*68 + b
    __shared__ float red[256];
    const int c0 = blockIdx.x * 8;
    const int t = threadIdx.x;
    for (int idx = t; idx < 16384; idx += 256) {
        int b = idx >> 8, r = idx & 255;
        vts[(r >> 6) * 4360 + (r & 63) * 68 + b] = v[idx];
    }
    for (int idx = t; idx < 4096; idx += 256) {
        int b = idx >> 6, r = idx & 63;
        xts[r * 68 + b] = xt[(long)b * 16192 + (long)c0 * 8 + r];
    }
    __syncthreads();
    const int cc = t >> 5, jj = (t >> 3) & 3, p = t & 7;
    float Wreg[8][8];
    const float* wb = W + (long)(c0 + cc) * 2048 + jj * 512;
    #pragma unroll
    for (int dd = 0; dd < 8; ++dd) {
        const int d = p + dd * 8;
        *(f32x4*)&Wreg[dd][0] = *(const f32x4*)(wb + d * 8);
        *(f32x4*)&Wreg[dd][4] = *(const f32x4*)(wb + d * 8 + 4);
    }
    float a0 = 0.f, a1 = 0.f, a2 = 0.f, a3 = 0.f;
    for (int b0 = 0; b0 < 64; b0 += 4) {
        float xq[8][4];
        #pragma unroll
        for (int i = 0; i < 8; ++i)
            *(f32x4*)&xq[i][0] = *(const f32x4*)&xts[(cc * 8 + i) * 68 + b0];
        #pragma unroll
        for (int dd = 0; dd < 8; ++dd) {
            const int d = p + dd * 8;
            f32x4 vq = *(const f32x4*)&vts[jj * 4360 + d * 68 + b0];
            float u0 = 0, u1 = 0, u2 = 0, u3 = 0;
            #pragma unroll
            for (int i = 0; i < 8; ++i) {
                const float wv = Wreg[dd][i];
                u0 += wv * xq[i][0]; u1 += wv * xq[i][1];
                u2 += wv * xq[i][2]; u3 += wv * xq[i][3];
            }
            a0 += u0 * vq[0]; a1 += u1 * vq[1]; a2 += u2 * vq[2]; a3 += u3 * vq[3];
        }
    }
    red[t] = a0 + a1 + a2 + a3;
    __syncthreads();
    if (p == 0) {
        float s = 0.f;
        #pragma unroll
        for (int q2 = 0; q2 < 8; ++q2) s += red[t + q2];
        s *= (1.0f / 64.0f);
        const int idx = (c0 + cc) * 4 + jj;
        bij[idx] = ADD ? (bij[idx] + s) : s;
    }
}

// ------------------------------------------------- K7: softmax over c per j
__global__ __launch_bounds__(256) void k_softmax(const float* __restrict__ bij,
                                                 float* __restrict__ cij) {
    __shared__ float red[256];
    const int j = blockIdx.x, t = threadIdx.x;
    float vals[8];
    float m = -1e30f;
    #pragma unroll
    for (int q = 0; q < 8; ++q) {
        const int c = q * 256 + t;
        const float z = (c < 2024) ? bij[c * 4 + j] : -1e30f;
        vals[q] = z;
        m = fmaxf(m, z);
    }
    red[t] = m;
    __syncthreads();
    for (int s = 128; s > 0; s >>= 1) {
        if (t < s) red[t] = fmaxf(red[t], red[t + s]);
        __syncthreads();
    }
    m = red[0];
    __syncthreads();
    float sum = 0.f;
    #pragma unroll
    for (int q = 0; q < 8; ++q) {
        const int c = q * 256 + t;
        const float e = (c < 2024) ? __expf(vals[q] - m) : 0.0f;
        vals[q] = e;
        sum += e;
    }
    red[t] = sum;
    __syncthreads();
    for (int s = 128; s > 0; s >>= 1) {
        if (t < s) red[t] += red[t + s];
        __syncthreads();
    }
    const float inv = 1.0f / red[0];
    #pragma unroll
    for (int q = 0; q < 8; ++q) {
        const int c = q * 256 + t;
        if (c < 2024) cij[j * 2024 + c] = vals[q] * inv;
    }
}

// ------------------------------------------------- K8: fc2 chain -> logits
__global__ __launch_bounds__(256) void k_fc2(const float* __restrict__ v,
                                             const float* __restrict__ w1, const float* __restrict__ b1,
                                             const float* __restrict__ w2, const float* __restrict__ b2,
                                             const float* __restrict__ w3, const float* __restrict__ b3,
                                             float* __restrict__ logits) {
    __shared__ float caps[256], h1[128], h2[64];
    const int b = blockIdx.x, t = threadIdx.x;
    caps[t] = v[b * 256 + t];
    __syncthreads();
    if (t < 128) {
        float s = b1[t];
        const float* wr = w1 + t * 256;
        for (int k = 0; k < 256; ++k) s += wr[k] * caps[k];
        h1[t] = (s >= 0.f) ? s : 0.01f * s;
    }
    __syncthreads();
    if (t < 64) {
        float s = b2[t];
        const float* wr = w2 + t * 128;
        for (int k = 0; k < 128; ++k) s += wr[k] * h1[k];
        h2[t] = (s >= 0.f) ? s : 0.01f * s;
    }
    __syncthreads();
    if (t < 2) {
        float s = b3[t];
        const float* wr = w3 + t * 64;
        for (int k = 0; k < 64; ++k) s += wr[k] * h2[k];
        logits[b * 2 + t] = s;
    }
}

extern "C" void kernel_launch(void* const* d_in, const int* in_sizes, int n_in,
                              void* d_out, int out_size, void* d_ws, size_t ws_size,
                              hipStream_t stream) {
    const float* x      = (const float*)d_in[0];
    const float* fc_w   = (const float*)d_in[1];
    const float* fc_b   = (const float*)d_in[2];
    const float* conv_w = (const float*)d_in[3];
    const float* conv_b = (const float*)d_in[4];
    const float* W_dig  = (const float*)d_in[5];
    const float* w1 = (const float*)d_in[6];
    const float* b1 = (const float*)d_in[7];
    const float* w2 = (const float*)d_in[8];
    const float* b2 = (const float*)d_in[9];
    const float* w3 = (const float*)d_in[10];
    const float* b3 = (const float*)d_in[11];

    float* out    = (float*)d_out;
    float* logits = out;        // [64,2]
    float* sdae   = out + 128;  // [64,512]

    float* ws     = (float*)d_ws;
    float* ws_fc  = ws;                    // 32*128*1024 = 4194304 f32
    float* ws_xt  = ws_fc + 4194304;       // 64*2024*8 = 1036288
    float* ws_sp  = ws_xt + 1036288;       // 256*4096 = 1048576
    float* ws_v   = ws_sp + 1048576;       // 16384
    float* ws_bij = ws_v + 16384;          // 8096
    float* ws_cij = ws_bij + 8096;         // 8096

    k_fc_gemm<<<1024, 256, 0, stream>>>(x, fc_w, ws_fc);
    k_fc_reduce<<<128, 256, 0, stream>>>(ws_fc, fc_b, sdae);
    k_conv_squash<<<64, 256, 0, stream>>>(sdae, conv_w, conv_b, ws_xt);

    // iteration 1 (uniform c_ij folded into route_s)
    k_route_s<1><<<256, 256, 0, stream>>>(W_dig, ws_xt, ws_cij, ws_sp);
    k_route_v<<<64, 256, 0, stream>>>(ws_sp, ws_v);
    // iteration 2
    k_route_a<0><<<253, 256, 0, stream>>>(W_dig, ws_xt, ws_v, ws_bij);
    k_softmax<<<4, 256, 0, stream>>>(ws_bij, ws_cij);
    k_route_s<0><<<256, 256, 0, stream>>>(W_dig, ws_xt, ws_cij, ws_sp);
    k_route_v<<<64, 256, 0, stream>>>(ws_sp, ws_v);
    // iteration 3 (final b_ij update in reference is dead -> skipped)
    k_route_a<1><<<253, 256, 0, stream>>>(W_dig, ws_xt, ws_v, ws_bij);
    k_softmax<<<4, 256, 0, stream>>>(ws_bij, ws_cij);
    k_route_s<0><<<256, 256, 0, stream>>>(W_dig, ws_xt, ws_cij, ws_sp);
    k_route_v<<<64, 256, 0, stream>>>(ws_sp, ws_v);

    k_fc2<<<64, 256, 0, stream>>>(ws_v, w1, b1, w2, b2, w3, b3, logits);
}

// Round 9
// 303.922 us; speedup vs baseline: 1.0482x; 1.0482x over previous
//
#include <hip/hip_runtime.h>
#include <hip/hip_bf16.h>

typedef __attribute__((ext_vector_type(8))) short s16x8;
typedef __attribute__((ext_vector_type(4))) float f32x4;

#define D_IN 227989
#define KSPLIT 128
#define KC 1792        // 28*64; KSPLIT*KC = 229376 >= D_IN
#define NSTEPS 28      // K-step 64
#define APITCH 68      // f32 row pitch: 272B; 68 mod 32 = 4 -> rows spread 8 bank-groups
#define BUFSZ (128 * APITCH)   // one buffer: A rows 0..63, B rows 64..127 (34 KiB)

// pack 8 f32 -> 8 bf16 (RNE) via v_cvt_pk_bf16_f32 (no builtin on gfx950).
// Plain asm (not volatile): inputs come from compiler-managed LDS loads with
// compiler-inserted waitcnts, so scheduling freedom is safe here.
__device__ __forceinline__ s16x8 pk2(f32x4 lo, f32x4 hi) {
    union { int i[4]; s16x8 s; } u;
    asm("v_cvt_pk_bf16_f32 %0, %1, %2" : "=v"(u.i[0]) : "v"(lo[0]), "v"(lo[1]));
    asm("v_cvt_pk_bf16_f32 %0, %1, %2" : "=v"(u.i[1]) : "v"(lo[2]), "v"(lo[3]));
    asm("v_cvt_pk_bf16_f32 %0, %1, %2" : "=v"(u.i[2]) : "v"(hi[0]), "v"(hi[1]));
    asm("v_cvt_pk_bf16_f32 %0, %1, %2" : "=v"(u.i[3]) : "v"(hi[2]), "v"(hi[3]));
    return u.s;
}

__device__ __forceinline__ s16x8 cvt8(const float* p) {   // p is 16B-aligned
    return pk2(*(const f32x4*)p, *(const f32x4*)(p + 4));
}

// async global->LDS dword: one instruction stages one contiguous 256B row chunk
__device__ __forceinline__ void gload_lds(const float* g, float* l) {
    __builtin_amdgcn_global_load_lds(
        (const __attribute__((address_space(1))) void*)g,
        (__attribute__((address_space(3))) void*)l, 4, 0, 0);
}

// wave stages its 16 A rows + 16 B rows of one K-step-64 tile (32 instrs)
__device__ __forceinline__ void stage_tile(const float* ga, const float* gb,
                                           float* lbase, int wid) {
    float* la = lbase + (wid * 16) * APITCH;
    float* lb = lbase + (64 + wid * 16) * APITCH;
    #pragma unroll
    for (int i = 0; i < 16; ++i) {
        gload_lds(ga + (long)i * D_IN, la + i * APITCH);
        gload_lds(gb + (long)i * D_IN, lb + i * APITCH);
    }
}

// one K-step-64 of MFMAs on a staged tile (all LDS reads 16B-aligned b128)
__device__ __forceinline__ void compute_tile(const float* buf, int wid,
                                             int frow, int koct, f32x4* acc) {
    const float* B = buf + (64 + wid * 16 + frow) * APITCH + koct * 8;
    const s16x8 b0 = cvt8(B);
    const s16x8 b1 = cvt8(B + 32);
    const float* A = buf + frow * APITCH + koct * 8;
    #pragma unroll
    for (int m = 0; m < 4; ++m) {
        const s16x8 a0 = cvt8(A + m * 16 * APITCH);
        const s16x8 a1 = cvt8(A + m * 16 * APITCH + 32);
        acc[m] = __builtin_amdgcn_mfma_f32_16x16x32_bf16(a0, b0, acc[m], 0, 0, 0);
        acc[m] = __builtin_amdgcn_mfma_f32_16x16x32_bf16(a1, b1, acc[m], 0, 0, 0);
    }
}

// ---------------------------------------------------------------- K1: FC GEMM
// C[64,512] = x[64,K] @ fc_w[512,K]^T, bf16 MFMA, K-split partials.
// Block tile M=64 x N=64 x K=64, 4 waves. QUAD-buffered LDS (136 KiB, 1
// block/CU), SINGLE barrier per K-step, 2-step-deep prefetch with counted
// vmcnt (63 steady / 32 / 0 at the tail) -- stage batches stay in flight
// across barriers; the wait for tile s was issued 2 steps (~3500 cyc) earlier,
// fully covering ~900-cyc HBM latency. Write-safety: buffer (s+2)&3 was
// computed at iter s-2, strictly before barrier(s-1), which precedes this
// stage. grid = 8 nt x 128 ks.
__global__ __launch_bounds__(256) void k_fc_gemm(const float* __restrict__ x,
                                                 const float* __restrict__ w,
                                                 float* __restrict__ part) {
    __shared__ __align__(16) float lds[4 * BUFSZ];
    const int t = threadIdx.x;
    const int wid = t >> 6, lane = t & 63;
    const int frow = lane & 15, koct = lane >> 4;
    const int bx = blockIdx.x;
    const int nt = bx & 7, ks = bx >> 3;
    const long k0 = (long)ks * KC;

    const float* ga = x + (long)(wid * 16) * D_IN + k0 + lane;
    const float* gb = w + (long)(nt * 64 + wid * 16) * D_IN + k0 + lane;

    f32x4 acc[4] = {};

    if (k0 + KC <= D_IN) {
        // -------- fast path (ks 0..126)
        stage_tile(ga, gb, lds + 0 * BUFSZ, wid);            // t0
        stage_tile(ga + 64, gb + 64, lds + 1 * BUFSZ, wid);  // t1
        #pragma unroll 1
        for (int s = 0; s < NSTEPS; ++s) {
            if (s + 2 < NSTEPS)
                stage_tile(ga + (s + 2) * 64, gb + (s + 2) * 64,
                           lds + ((s + 2) & 3) * BUFSZ, wid);
            // counted wait: tile s fully landed; newer batches stay in flight
            if (s + 2 < NSTEPS)      asm volatile("s_waitcnt vmcnt(63)" ::: "memory");
            else if (s + 1 < NSTEPS) asm volatile("s_waitcnt vmcnt(32)" ::: "memory");
            else                     asm volatile("s_waitcnt vmcnt(0)"  ::: "memory");
            __builtin_amdgcn_s_barrier();
            asm volatile("" ::: "memory");
            compute_tile(lds + (s & 3) * BUFSZ, wid, frow, koct, acc);
        }
    } else {
        // -------- tail block (ks == 127, rem = 405): predicated reg-staging
        const int rem = (int)(D_IN - k0);
        const int nst = (rem + 63) >> 6;
        for (int s = 0; s < nst; ++s) {
            const int kk = s * 64 + lane;
            const bool ok = kk < rem;
            float va[16], vb[16];
            #pragma unroll
            for (int i = 0; i < 16; ++i) {
                va[i] = ok ? ga[(long)i * D_IN + s * 64] : 0.0f;
                vb[i] = ok ? gb[(long)i * D_IN + s * 64] : 0.0f;
            }
            __syncthreads();
            #pragma unroll
            for (int i = 0; i < 16; ++i) {
                lds[(wid * 16 + i) * APITCH + lane] = va[i];
                lds[(64 + wid * 16 + i) * APITCH + lane] = vb[i];
            }
            __syncthreads();
            compute_tile(lds, wid, frow, koct, acc);
        }
    }

    // partials: chunk (g16, ks) holds [64 m][16 n]; g16 = global 16-col group
    const int g16 = nt * 4 + wid;
    float* __restrict__ po = part + ((long)(g16 * KSPLIT + ks) << 10);
    #pragma unroll
    for (int m = 0; m < 4; ++m)
        #pragma unroll
        for (int r = 0; r < 4; ++r)
            po[(m * 16 + koct * 4 + r) * 16 + frow] = acc[m][r];
}

// ------------------------------------------------- K2: reduce + bias + ReLU
__global__ __launch_bounds__(256) void k_fc_reduce(const float* __restrict__ part,
                                                   const float* __restrict__ bias,
                                                   float* __restrict__ sdae) {
    const int i = blockIdx.x * 256 + threadIdx.x;  // 32768
    const int m = i >> 9, n = i & 511;
    const int nt = n >> 4, nl = n & 15;
    const float* p = part + ((long)nt * KSPLIT << 10) + m * 16 + nl;
    float s = 0.f;
    #pragma unroll 4
    for (int ks = 0; ks < KSPLIT; ++ks) s += p[(long)ks << 10];
    s += bias[n];
    sdae[i] = fmaxf(s, 0.0f);
}

// ------------------------------------------------- K3: conv + squash -> xt
// xt[b][c][i] with c = co*253+l, i = nu.  grid 64 (b), block 256.
__global__ __launch_bounds__(256) void k_conv_squash(const float* __restrict__ sdae,
                                                     const float* __restrict__ cw,
                                                     const float* __restrict__ cb,
                                                     float* __restrict__ xt) {
    __shared__ float row_s[512];
    __shared__ float us[64 * 253];
    __shared__ float part[256];
    __shared__ float scale_s[8];
    const int b = blockIdx.x, t = threadIdx.x;
    row_s[t] = sdae[b * 512 + t];
    row_s[t + 256] = sdae[b * 512 + t + 256];
    __syncthreads();
    const int ch = t >> 2, lq = t & 3;
    float wreg[8];
    #pragma unroll
    for (int k = 0; k < 8; ++k) wreg[k] = cw[ch * 8 + k];
    const float bias = cb[ch];
    const int l0 = lq * 64;
    const int l1 = (lq == 3) ? 253 : (l0 + 64);
    float ssq = 0.f;
    for (int l = l0; l < l1; ++l) {
        float v = bias;
        #pragma unroll
        for (int k = 0; k < 8; ++k) v += row_s[2 * l + k] * wreg[k];
        us[ch * 253 + l] = v;
        ssq += v * v;
    }
    part[t] = ssq;
    __syncthreads();
    if (t < 8) {
        float s = 0.f;
        for (int i = 0; i < 32; ++i) s += part[t * 32 + i];
        scale_s[t] = sqrtf(s) / (1.0f + s);  // mag_sq/(1+mag_sq)/mag == mag/(1+mag_sq)
    }
    __syncthreads();
    const int nu = ch >> 3, co = ch & 7;
    const float sc = scale_s[nu];
    for (int l = l0; l < l1; ++l)
        xt[(long)b * 16192 + (long)(co * 253 + l) * 8 + nu] = us[ch * 253 + l] * sc;
}

// ------------------------------------------------- K4: s_j partials
// s[b,j,d] = sum_{c,i} (cij[j,c]*W[c,j,d,i]) * xt[b,c,i]
// grid = 4j * 64 csplit = 256; block 256; each WG all b,d over 32 c's.
// UNIFORM=1: first routing iteration, c_ij == 1/2024 (no cij read).
template <int UNIFORM>
__global__ __launch_bounds__(256) void k_route_s(const float* __restrict__ W,
                                                 const float* __restrict__ xt,
                                                 const float* __restrict__ cij,
                                                 float* __restrict__ spart) {
    __shared__ __align__(16) float xs[64 * 132];   // [b][128+pad]
    __shared__ __align__(16) float wsh[16 * 768];  // [cc][d*12]
    const int bx = blockIdx.x;
    const int j = bx >> 6, cs = bx & 63;
    const int c0 = cs * 32;
    const int t = threadIdx.x;
    const int bg = t >> 4, dg = t & 15;
    float acc[4][4] = {};
    #pragma unroll 1
    for (int cc0 = 0; cc0 < 32; cc0 += 16) {
        {
            const int bb = t >> 2, p = t & 3;
            const float* src = xt + (long)bb * 16192 + (long)(c0 + cc0) * 8 + p * 32;
            float* dst = &xs[bb * 132 + p * 32];
            if (c0 + cc0 + 16 <= 2024) {
                #pragma unroll
                for (int e = 0; e < 32; e += 4) *(f32x4*)(dst + e) = *(const f32x4*)(src + e);
            } else {
                for (int e = 0; e < 32; ++e) {
                    int cidx = c0 + cc0 + ((p * 32 + e) >> 3);
                    dst[e] = (cidx < 2024) ? src[e] : 0.0f;
                }
            }
        }
        {
            const int ccs = t >> 4, dp = t & 15;
            const int c = c0 + cc0 + ccs;
            float* o = &wsh[ccs * 768 + dp * 48];
            if (c < 2024) {
                const float sc = UNIFORM ? (1.0f / 2024.0f) : cij[j * 2024 + c];
                const float* wsrc = W + (long)c * 2048 + j * 512 + dp * 32;
                #pragma unroll
                for (int dd = 0; dd < 4; ++dd) {
                    f32x4 w0 = *(const f32x4*)(wsrc + dd * 8);
                    f32x4 w1 = *(const f32x4*)(wsrc + dd * 8 + 4);
                    float* od = o + dd * 12;
                    od[0] = w0[0] * sc; od[1] = w0[1] * sc; od[2] = w0[2] * sc; od[3] = w0[3] * sc;
                    od[4] = w1[0] * sc; od[5] = w1[1] * sc; od[6] = w1[2] * sc; od[7] = w1[3] * sc;
                }
            } else {
                #pragma unroll
                for (int dd = 0; dd < 4; ++dd) {
                    float* od = o + dd * 12;
                    #pragma unroll
                    for (int e = 0; e < 8; ++e) od[e] = 0.0f;
                }
            }
        }
        __syncthreads();
        int ccN = 2024 - c0 - cc0;
        if (ccN > 16) ccN = 16;
        for (int cc = 0; cc < ccN; ++cc) {
            float xv[4][8], wv[4][8];
            #pragma unroll
            for (int bb = 0; bb < 4; ++bb) {
                *(f32x4*)&xv[bb][0] = *(const f32x4*)&xs[(bg * 4 + bb) * 132 + cc * 8];
                *(f32x4*)&xv[bb][4] = *(const f32x4*)&xs[(bg * 4 + bb) * 132 + cc * 8 + 4];
            }
            #pragma unroll
            for (int dd = 0; dd < 4; ++dd) {
                const int d = dg + dd * 16;
                *(f32x4*)&wv[dd][0] = *(const f32x4*)&wsh[cc * 768 + d * 12];
                *(f32x4*)&wv[dd][4] = *(const f32x4*)&wsh[cc * 768 + d * 12 + 4];
            }
            #pragma unroll
            for (int bb = 0; bb < 4; ++bb)
                #pragma unroll
                for (int dd = 0; dd < 4; ++dd)
                    #pragma unroll
                    for (int i = 0; i < 8; ++i)
                        acc[bb][dd] += xv[bb][i] * wv[dd][i];
        }
        __syncthreads();
    }
    float* sp = spart + ((long)bx << 12);
    #pragma unroll
    for (int bb = 0; bb < 4; ++bb)
        #pragma unroll
        for (int dd = 0; dd < 4; ++dd)
            sp[(bg * 4 + bb) * 64 + dg + dd * 16] = acc[bb][dd];
}

// ------------------------------------------------- K5: reduce s + squash(j) -> v
__global__ __launch_bounds__(256) void k_route_v(const float* __restrict__ spart,
                                                 float* __restrict__ v) {
    __shared__ float sj[256];
    const int b = blockIdx.x, t = threadIdx.x;
    const int d = t & 63;
    const int j = t >> 6;
    float s = 0.f;
    #pragma unroll 4
    for (int cs = 0; cs < 64; ++cs)
        s += spart[((long)(j * 64 + cs) << 12) + (b << 6) + d];
    sj[t] = s;
    __syncthreads();
    float msq = 0.f;
    #pragma unroll
    for (int q = 0; q < 4; ++q) { float z = sj[q * 64 + d]; msq += z * z; }
    v[(b << 8) + t] = s * (sqrtf(msq) / (1.0f + msq));
}

// ------------------------------------------------- K6: agreement -> b_ij
// grid 253 (8 c's each), block 256 = (cc8, j4, p8).
template <int ADD>
__global__ __launch_bounds__(256) void k_route_a(const float* __restrict__ W,
                                                 const float* __restrict__ xt,
                                                 const float* __restrict__ v,
                                                 float* __restrict__ bij) {
    __shared__ __align__(16) float xts[64 * 68];   // [cc*8+i][b]
    __shared__ __align__(16) float vts[4 * 4360];  // j*4360 + d*68 + b
    __shared__ float red[256];
    const int c0 = blockIdx.x * 8;
    const int t = threadIdx.x;
    for (int idx = t; idx < 16384; idx += 256) {
        int b = idx >> 8, r = idx & 255;
        vts[(r >> 6) * 4360 + (r & 63) * 68 + b] = v[idx];
    }
    for (int idx = t; idx < 4096; idx += 256) {
        int b = idx >> 6, r = idx & 63;
        xts[r * 68 + b] = xt[(long)b * 16192 + (long)c0 * 8 + r];
    }
    __syncthreads();
    const int cc = t >> 5, jj = (t >> 3) & 3, p = t & 7;
    float Wreg[8][8];
    const float* wb = W + (long)(c0 + cc) * 2048 + jj * 512;
    #pragma unroll
    for (int dd = 0; dd < 8; ++dd) {
        const int d = p + dd * 8;
        *(f32x4*)&Wreg[dd][0] = *(const f32x4*)(wb + d * 8);
        *(f32x4*)&Wreg[dd][4] = *(const f32x4*)(wb + d * 8 + 4);
    }
    float a0 = 0.f, a1 = 0.f, a2 = 0.f, a3 = 0.f;
    for (int b0 = 0; b0 < 64; b0 += 4) {
        float xq[8][4];
        #pragma unroll
        for (int i = 0; i < 8; ++i)
            *(f32x4*)&xq[i][0] = *(const f32x4*)&xts[(cc * 8 + i) * 68 + b0];
        #pragma unroll
        for (int dd = 0; dd < 8; ++dd) {
            const int d = p + dd * 8;
            f32x4 vq = *(const f32x4*)&vts[jj * 4360 + d * 68 + b0];
            float u0 = 0, u1 = 0, u2 = 0, u3 = 0;
            #pragma unroll
            for (int i = 0; i < 8; ++i) {
                const float wv = Wreg[dd][i];
                u0 += wv * xq[i][0]; u1 += wv * xq[i][1];
                u2 += wv * xq[i][2]; u3 += wv * xq[i][3];
            }
            a0 += u0 * vq[0]; a1 += u1 * vq[1]; a2 += u2 * vq[2]; a3 += u3 * vq[3];
        }
    }
    red[t] = a0 + a1 + a2 + a3;
    __syncthreads();
    if (p == 0) {
        float s = 0.f;
        #pragma unroll
        for (int q2 = 0; q2 < 8; ++q2) s += red[t + q2];
        s *= (1.0f / 64.0f);
        const int idx = (c0 + cc) * 4 + jj;
        bij[idx] = ADD ? (bij[idx] + s) : s;
    }
}

// ------------------------------------------------- K7: softmax over c per j
__global__ __launch_bounds__(256) void k_softmax(const float* __restrict__ bij,
                                                 float* __restrict__ cij) {
    __shared__ float red[256];
    const int j = blockIdx.x, t = threadIdx.x;
    float vals[8];
    float m = -1e30f;
    #pragma unroll
    for (int q = 0; q < 8; ++q) {
        const int c = q * 256 + t;
        const float z = (c < 2024) ? bij[c * 4 + j] : -1e30f;
        vals[q] = z;
        m = fmaxf(m, z);
    }
    red[t] = m;
    __syncthreads();
    for (int s = 128; s > 0; s >>= 1) {
        if (t < s) red[t] = fmaxf(red[t], red[t + s]);
        __syncthreads();
    }
    m = red[0];
    __syncthreads();
    float sum = 0.f;
    #pragma unroll
    for (int q = 0; q < 8; ++q) {
        const int c = q * 256 + t;
        const float e = (c < 2024) ? __expf(vals[q] - m) : 0.0f;
        vals[q] = e;
        sum += e;
    }
    red[t] = sum;
    __syncthreads();
    for (int s = 128; s > 0; s >>= 1) {
        if (t < s) red[t] += red[t + s];
        __syncthreads();
    }
    const float inv = 1.0f / red[0];
    #pragma unroll
    for (int q = 0; q < 8; ++q) {
        const int c = q * 256 + t;
        if (c < 2024) cij[j * 2024 + c] = vals[q] * inv;
    }
}

// ------------------------------------------------- K8: fc2 chain -> logits
__global__ __launch_bounds__(256) void k_fc2(const float* __restrict__ v,
                                             const float* __restrict__ w1, const float* __restrict__ b1,
                                             const float* __restrict__ w2, const float* __restrict__ b2,
                                             const float* __restrict__ w3, const float* __restrict__ b3,
                                             float* __restrict__ logits) {
    __shared__ float caps[256], h1[128], h2[64];
    const int b = blockIdx.x, t = threadIdx.x;
    caps[t] = v[b * 256 + t];
    __syncthreads();
    if (t < 128) {
        float s = b1[t];
        const float* wr = w1 + t * 256;
        for (int k = 0; k < 256; ++k) s += wr[k] * caps[k];
        h1[t] = (s >= 0.f) ? s : 0.01f * s;
    }
    __syncthreads();
    if (t < 64) {
        float s = b2[t];
        const float* wr = w2 + t * 128;
        for (int k = 0; k < 128; ++k) s += wr[k] * h1[k];
        h2[t] = (s >= 0.f) ? s : 0.01f * s;
    }
    __syncthreads();
    if (t < 2) {
        float s = b3[t];
        const float* wr = w3 + t * 64;
        for (int k = 0; k < 64; ++k) s += wr[k] * h2[k];
        logits[b * 2 + t] = s;
    }
}

extern "C" void kernel_launch(void* const* d_in, const int* in_sizes, int n_in,
                              void* d_out, int out_size, void* d_ws, size_t ws_size,
                              hipStream_t stream) {
    const float* x      = (const float*)d_in[0];
    const float* fc_w   = (const float*)d_in[1];
    const float* fc_b   = (const float*)d_in[2];
    const float* conv_w = (const float*)d_in[3];
    const float* conv_b = (const float*)d_in[4];
    const float* W_dig  = (const float*)d_in[5];
    const float* w1 = (const float*)d_in[6];
    const float* b1 = (const float*)d_in[7];
    const float* w2 = (const float*)d_in[8];
    const float* b2 = (const float*)d_in[9];
    const float* w3 = (const float*)d_in[10];
    const float* b3 = (const float*)d_in[11];

    float* out    = (float*)d_out;
    float* logits = out;        // [64,2]
    float* sdae   = out + 128;  // [64,512]

    float* ws     = (float*)d_ws;
    float* ws_fc  = ws;                    // 32*128*1024 = 4194304 f32
    float* ws_xt  = ws_fc + 4194304;       // 64*2024*8 = 1036288
    float* ws_sp  = ws_xt + 1036288;       // 256*4096 = 1048576
    float* ws_v   = ws_sp + 1048576;       // 16384
    float* ws_bij = ws_v + 16384;          // 8096
    float* ws_cij = ws_bij + 8096;         // 8096

    k_fc_gemm<<<1024, 256, 0, stream>>>(x, fc_w, ws_fc);
    k_fc_reduce<<<128, 256, 0, stream>>>(ws_fc, fc_b, sdae);
    k_conv_squash<<<64, 256, 0, stream>>>(sdae, conv_w, conv_b, ws_xt);

    // iteration 1 (uniform c_ij folded into route_s)
    k_route_s<1><<<256, 256, 0, stream>>>(W_dig, ws_xt, ws_cij, ws_sp);
    k_route_v<<<64, 256, 0, stream>>>(ws_sp, ws_v);
    // iteration 2
    k_route_a<0><<<253, 256, 0, stream>>>(W_dig, ws_xt, ws_v, ws_bij);
    k_softmax<<<4, 256, 0, stream>>>(ws_bij, ws_cij);
    k_route_s<0><<<256, 256, 0, stream>>>(W_dig, ws_xt, ws_cij, ws_sp);
    k_route_v<<<64, 256, 0, stream>>>(ws_sp, ws_v);
    // iteration 3 (final b_ij update in reference is dead -> skipped)
    k_route_a<1><<<253, 256, 0, stream>>>(W_dig, ws_xt, ws_v, ws_bij);
    k_softmax<<<4, 256, 0, stream>>>(ws_bij, ws_cij);
    k_route_s<0><<<256, 256, 0, stream>>>(W_dig, ws_xt, ws_cij, ws_sp);
    k_route_v<<<64, 256, 0, stream>>>(ws_sp, ws_v);

    k_fc2<<<64, 256, 0, stream>>>(ws_v, w1, b1, w2, b2, w3, b3, logits);
}